// Round 6
// baseline (1580.585 us; speedup 1.0000x reference)
//
#include <hip/hip_runtime.h>

#define NN 100000
#define NE 1600000
#define DD 128
#define NG 512
#define ZCOLS 384
#define TM 32

// ---------------- CSR build (counting sort by dst) ----------------
__global__ __launch_bounds__(256) void k_hist(const int* __restrict__ dst, int* __restrict__ cnt) {
    for (int e = blockIdx.x * blockDim.x + threadIdx.x; e < NE; e += gridDim.x * blockDim.x)
        atomicAdd(&cnt[dst[e]], 1);
}

__global__ __launch_bounds__(1024) void k_scan(const int* __restrict__ cnt, int* __restrict__ off,
                                               int* __restrict__ cur) {
    __shared__ int s[1024];
    const int t = threadIdx.x;
    const int CH = (NN + 1023) / 1024;  // 98
    const int base = t * CH;
    int loc = 0;
    for (int i = 0; i < CH; i++) { int idx = base + i; if (idx < NN) loc += cnt[idx]; }
    s[t] = loc;
    __syncthreads();
    for (int st = 1; st < 1024; st <<= 1) {
        int v = (t >= st) ? s[t - st] : 0;
        __syncthreads();
        s[t] += v;
        __syncthreads();
    }
    int run = s[t] - loc;  // exclusive prefix
    for (int i = 0; i < CH; i++) {
        int idx = base + i;
        if (idx < NN) { off[idx] = run; cur[idx] = run; run += cnt[idx]; }
    }
    if (t == 1023) off[NN] = s[1023];
}

__global__ __launch_bounds__(256) void k_scatter(const int* __restrict__ src, const int* __restrict__ dst,
                                                 int* __restrict__ cur, int* __restrict__ ss) {
    for (int e = blockIdx.x * blockDim.x + threadIdx.x; e < NE; e += gridDim.x * blockDim.x) {
        int p = atomicAdd(&cur[dst[e]], 1);
        ss[p] = src[e];
    }
}

// ---------------- bf16 helpers ----------------
__device__ __forceinline__ float bf_lo(unsigned u) { return __uint_as_float(u << 16); }
__device__ __forceinline__ float bf_hi(unsigned u) { return __uint_as_float(u & 0xFFFF0000u); }
__device__ __forceinline__ unsigned pack_bf16(float a, float b) {
    unsigned ua = __float_as_uint(a), ub = __float_as_uint(b);
    ua = (ua + 0x7FFFu + ((ua >> 16) & 1u)) >> 16;
    ub = (ub + 0x7FFFu + ((ub >> 16) & 1u)) >> 16;
    return (ub << 16) | ua;
}

// x (fp32 [NN][128]) -> packed bf16 [NN][64 uints]
__global__ __launch_bounds__(256) void k_xcast(const float* __restrict__ x, unsigned* __restrict__ xb) {
    int gid = blockIdx.x * blockDim.x + threadIdx.x;
    if (gid >= NN * 64) return;
    int i = gid >> 6, ln = gid & 63;
    float2 v = *(const float2*)(x + (size_t)i * DD + 2 * ln);
    xb[gid] = pack_bf16(v.x, v.y);
}

// ---------------- gather: one wave per node, no LDS, no barriers ----------------
// agg[i] = z[i] + sum_{src in CSR[i]} z[src]  (packed bf16 in, packed bf16 out)
__global__ __launch_bounds__(256) void k_gather(const unsigned* __restrict__ zb,
                                                const int* __restrict__ off, const int* __restrict__ ss,
                                                unsigned* __restrict__ aggb) {
    const int wv = threadIdx.x >> 6, ln = threadIdx.x & 63;
    const int i = blockIdx.x * 4 + wv;
    if (i >= NN) return;
    unsigned u = zb[(size_t)i * 64 + ln];
    float ax = bf_lo(u), ay = bf_hi(u);
    const int e0 = off[i], e1 = off[i + 1];
    int k = e0;
    for (; k + 8 <= e1; k += 8) {
        int i0 = ss[k], i1 = ss[k + 1], i2 = ss[k + 2], i3 = ss[k + 3];
        int i4 = ss[k + 4], i5 = ss[k + 5], i6 = ss[k + 6], i7 = ss[k + 7];
        unsigned u0 = zb[(size_t)i0 * 64 + ln], u1 = zb[(size_t)i1 * 64 + ln];
        unsigned u2 = zb[(size_t)i2 * 64 + ln], u3 = zb[(size_t)i3 * 64 + ln];
        unsigned u4 = zb[(size_t)i4 * 64 + ln], u5 = zb[(size_t)i5 * 64 + ln];
        unsigned u6 = zb[(size_t)i6 * 64 + ln], u7 = zb[(size_t)i7 * 64 + ln];
        ax += bf_lo(u0) + bf_lo(u1) + bf_lo(u2) + bf_lo(u3)
            + bf_lo(u4) + bf_lo(u5) + bf_lo(u6) + bf_lo(u7);
        ay += bf_hi(u0) + bf_hi(u1) + bf_hi(u2) + bf_hi(u3)
            + bf_hi(u4) + bf_hi(u5) + bf_hi(u6) + bf_hi(u7);
    }
    for (; k < e1; ++k) {
        unsigned uu = zb[(size_t)ss[k] * 64 + ln];
        ax += bf_lo(uu); ay += bf_hi(uu);
    }
    aggb[(size_t)i * 64 + ln] = pack_bf16(ax, ay);
}

// ---------------- MLP + BN-stats (uniform work per block) ----------------
__device__ __forceinline__ void tile_gemm(const float (*A)[DD + 4], const float* __restrict__ W,
                                          const float* __restrict__ bias, int r0, int c0,
                                          float acc[2][8]) {
    const float4 ba = *(const float4*)(bias + c0);
    const float4 bb = *(const float4*)(bias + c0 + 4);
#pragma unroll
    for (int i = 0; i < 2; i++) {
        acc[i][0] = ba.x; acc[i][1] = ba.y; acc[i][2] = ba.z; acc[i][3] = ba.w;
        acc[i][4] = bb.x; acc[i][5] = bb.y; acc[i][6] = bb.z; acc[i][7] = bb.w;
    }
    for (int k = 0; k < DD; k += 4) {
        float4 a0 = *(const float4*)&A[r0][k];
        float4 a1 = *(const float4*)&A[r0 + 1][k];
        float av0[4] = {a0.x, a0.y, a0.z, a0.w};
        float av1[4] = {a1.x, a1.y, a1.z, a1.w};
#pragma unroll
        for (int kk = 0; kk < 4; kk++) {
            const float* wr = W + (k + kk) * DD + c0;
            float4 wa = *(const float4*)wr;
            float4 wb = *(const float4*)(wr + 4);
            float w[8] = {wa.x, wa.y, wa.z, wa.w, wb.x, wb.y, wb.z, wb.w};
#pragma unroll
            for (int j = 0; j < 8; j++) {
                acc[0][j] = fmaf(av0[kk], w[j], acc[0][j]);
                acc[1][j] = fmaf(av1[kk], w[j], acc[1][j]);
            }
        }
    }
}

__global__ __launch_bounds__(256) void k_mlp(
    const unsigned* __restrict__ aggb,
    const float* __restrict__ W1, const float* __restrict__ b1,
    const float* __restrict__ W2, const float* __restrict__ b2,
    float* __restrict__ hout,  // d_out + l*128, row stride ZCOLS; raw h
    float* __restrict__ s1, float* __restrict__ s2) {
    __shared__ float buf[TM][DD + 4];
    const int tid = threadIdx.x;
    const int node0 = blockIdx.x * TM;

    // stage agg tile (bf16 -> fp32 LDS)
    for (int idx = tid; idx < TM * 64; idx += 256) {
        int r = idx >> 6, c = idx & 63;
        int node = node0 + r;
        unsigned u = (node < NN) ? aggb[(size_t)node * 64 + c] : 0u;
        buf[r][2 * c] = bf_lo(u);
        buf[r][2 * c + 1] = bf_hi(u);
    }
    __syncthreads();

    const int tx = tid & 15, ty = tid >> 4;
    const int c0 = tx * 8, r0 = ty * 2;

    // ---- GEMM1 + ReLU ----
    float acc[2][8];
    tile_gemm(buf, W1, b1, r0, c0, acc);
    float r1[2][8];
#pragma unroll
    for (int i = 0; i < 2; i++)
#pragma unroll
        for (int j = 0; j < 8; j++) r1[i][j] = fmaxf(acc[i][j], 0.f);
    __syncthreads();  // done reading buf(agg)
#pragma unroll
    for (int i = 0; i < 2; i++)
#pragma unroll
        for (int j = 0; j < 8; j++) buf[r0 + i][c0 + j] = r1[i][j];
    __syncthreads();

    // ---- GEMM2 -> raw h ----
    tile_gemm(buf, W2, b2, r0, c0, acc);

#pragma unroll
    for (int i = 0; i < 2; i++) {
        int node = node0 + r0 + i;
        if (node < NN) {
            float* op = hout + (size_t)node * ZCOLS + c0;
            *(float4*)op = make_float4(acc[i][0], acc[i][1], acc[i][2], acc[i][3]);
            *(float4*)(op + 4) = make_float4(acc[i][4], acc[i][5], acc[i][6], acc[i][7]);
        }
    }

    // ---- per-block column sum / sumsq -> global atomics ----
    float sv[8], qv[8];
#pragma unroll
    for (int j = 0; j < 8; j++) { sv[j] = 0.f; qv[j] = 0.f; }
#pragma unroll
    for (int i = 0; i < 2; i++) {
        if (node0 + r0 + i < NN) {
#pragma unroll
            for (int j = 0; j < 8; j++) { float v = acc[i][j]; sv[j] += v; qv[j] += v * v; }
        }
    }
    float2* red = (float2*)&buf[0][0];  // 16 KB, fits
    __syncthreads();                    // done reading buf(h1)
#pragma unroll
    for (int j = 0; j < 8; j++) red[ty * DD + c0 + j] = make_float2(sv[j], qv[j]);
    __syncthreads();
    for (int st = 8; st >= 1; st >>= 1) {
        if (ty < st) {
#pragma unroll
            for (int j = 0; j < 8; j++) {
                float2 a = red[ty * DD + c0 + j];
                float2 b = red[(ty + st) * DD + c0 + j];
                red[ty * DD + c0 + j] = make_float2(a.x + b.x, a.y + b.y);
            }
        }
        __syncthreads();
    }
    if (tid < DD) {
        float2 v = red[tid];
        atomicAdd(&s1[tid], v.x);
        atomicAdd(&s2[tid], v.y);
    }
}

// ---------------- BN finalize+apply (+optional packed-bf16 z emit) ----------------
__global__ __launch_bounds__(256) void k_bnapply(float* __restrict__ hout,
                                                 const float* __restrict__ s1, const float* __restrict__ s2,
                                                 const float* __restrict__ gamma, const float* __restrict__ beta,
                                                 unsigned* __restrict__ zb_out, int relu) {
    int gid = blockIdx.x * blockDim.x + threadIdx.x;
    if (gid >= NN * 32) return;
    int i = gid >> 5, q = gid & 31;
    int c = q * 4;
    float4 m4 = *(const float4*)(s1 + c);
    float4 q4 = *(const float4*)(s2 + c);
    float4 g4 = *(const float4*)(gamma + c);
    float4 be4 = *(const float4*)(beta + c);
    float A[4], B[4];
    {
        float m[4] = {m4.x, m4.y, m4.z, m4.w};
        float s[4] = {q4.x, q4.y, q4.z, q4.w};
        float g[4] = {g4.x, g4.y, g4.z, g4.w};
        float bb[4] = {be4.x, be4.y, be4.z, be4.w};
#pragma unroll
        for (int j = 0; j < 4; j++) {
            float mean = m[j] * (1.0f / NN);
            float var = s[j] * (1.0f / NN) - mean * mean;
            float a = g[j] * rsqrtf(var + 1e-5f);
            A[j] = a;
            B[j] = bb[j] - mean * a;
        }
    }
    float4* p = (float4*)(hout + (size_t)i * ZCOLS + c);
    float4 v = *p;
    v.x = v.x * A[0] + B[0];
    v.y = v.y * A[1] + B[1];
    v.z = v.z * A[2] + B[2];
    v.w = v.w * A[3] + B[3];
    if (relu) {
        v.x = fmaxf(v.x, 0.f); v.y = fmaxf(v.y, 0.f);
        v.z = fmaxf(v.z, 0.f); v.w = fmaxf(v.w, 0.f);
    }
    *p = v;
    if (zb_out) {
        uint2 w;
        w.x = pack_bf16(v.x, v.y);
        w.y = pack_bf16(v.z, v.w);
        *(uint2*)(zb_out + (size_t)i * 64 + 2 * q) = w;
    }
}

// ---------------- graph pooling (batch is sorted) ----------------
__global__ __launch_bounds__(256) void k_pool(const float* __restrict__ zc, const int* __restrict__ batch,
                                              float* __restrict__ g) {
    const int gr = blockIdx.x;
    int lo = 0, hi = NN;
    while (lo < hi) { int mid = (lo + hi) >> 1; if (batch[mid] < gr) lo = mid + 1; else hi = mid; }
    const int start = lo;
    hi = NN;
    while (lo < hi) { int mid = (lo + hi) >> 1; if (batch[mid] < gr + 1) lo = mid + 1; else hi = mid; }
    const int end = lo;

    const int tid = threadIdx.x;
    const int h = tid >> 7, c = tid & 127;
    float a0 = 0.f, a1 = 0.f, a2 = 0.f;
    for (int r = start + h; r < end; r += 2) {
        const float* row = zc + (size_t)r * ZCOLS;
        a0 += row[c];
        a1 += row[c + DD];
        a2 += row[c + 2 * DD];
    }
    __shared__ float red[3][256];
    red[0][tid] = a0; red[1][tid] = a1; red[2][tid] = a2;
    __syncthreads();
    if (tid < 128) {
        float* gp = g + (size_t)gr * ZCOLS;
        gp[c] = red[0][tid] + red[0][tid + 128];
        gp[c + DD] = red[1][tid] + red[1][tid + 128];
        gp[c + 2 * DD] = red[2][tid] + red[2][tid + 128];
    }
}

extern "C" void kernel_launch(void* const* d_in, const int* in_sizes, int n_in,
                              void* d_out, int out_size, void* d_ws, size_t ws_size,
                              hipStream_t stream) {
    const float* x = (const float*)d_in[0];
    const int* ei = (const int*)d_in[1];
    const int* batch = (const int*)d_in[2];
    const float* W1 = (const float*)d_in[3];
    const float* b1 = (const float*)d_in[4];
    const float* W2 = (const float*)d_in[5];
    const float* b2 = (const float*)d_in[6];
    const float* gamma = (const float*)d_in[7];
    const float* beta = (const float*)d_in[8];
    float* out = (float*)d_out;

    const int* esrc = ei;        // edge_index[0]
    const int* edst = ei + NE;   // edge_index[1]

    int* cnt = (int*)d_ws;            // N
    int* off = cnt + NN;              // N+1
    int* cur = off + NN + 1;          // N
    int* ss = cur + NN;               // E
    float* st = (float*)(ss + NE);    // 3 layers x 2 x 128 stats
    uintptr_t zbase = (uintptr_t)(st + 6 * DD);
    zbase = (zbase + 255) & ~(uintptr_t)255;
    unsigned* bufA = (unsigned*)zbase;              // z bf16 (recycled each layer)
    unsigned* bufB = bufA + (size_t)NN * 64;        // agg bf16 (recycled each layer)

    hipMemsetAsync(cnt, 0, NN * sizeof(int), stream);
    hipMemsetAsync(st, 0, 6 * DD * sizeof(float), stream);
    k_hist<<<2048, 256, 0, stream>>>(edst, cnt);
    k_scan<<<1, 1024, 0, stream>>>(cnt, off, cur);
    k_scatter<<<2048, 256, 0, stream>>>(esrc, edst, cur, ss);
    k_xcast<<<(NN * 64 + 255) / 256, 256, 0, stream>>>(x, bufA);

    float* gout = out + (size_t)NN * ZCOLS;
    for (int l = 0; l < 3; l++) {
        float* s1 = st + l * 2 * DD;
        float* s2 = s1 + DD;
        // gather reads bufA (z of prev layer / x), writes agg to bufB;
        // bnapply rewrites bufA with this layer's z (safe: gather already consumed it)
        k_gather<<<(NN + 3) / 4, 256, 0, stream>>>(bufA, off, ss, bufB);
        k_mlp<<<(NN + TM - 1) / TM, 256, 0, stream>>>(
            bufB, W1 + l * DD * DD, b1 + l * DD, W2 + l * DD * DD, b2 + l * DD,
            out + l * DD, s1, s2);
        k_bnapply<<<(NN * 32 + 255) / 256, 256, 0, stream>>>(
            out + l * DD, s1, s2, gamma + l * DD, beta + l * DD,
            (l < 2) ? bufA : nullptr, (l < 2) ? 1 : 0);
    }
    k_pool<<<NG, 256, 0, stream>>>(out, batch, gout);
}

// Round 7
// 1344.992 us; speedup vs baseline: 1.1752x; 1.1752x over previous
//
#include <hip/hip_runtime.h>

#define NN 100000
#define NE 1600000
#define DD 128
#define NG 512
#define ZCOLS 384
#define TM 32
#define SCAN_NB ((NN + 1023) / 1024)  // 98

// ---------------- CSR build (counting sort by dst) ----------------
__global__ __launch_bounds__(256) void k_hist(const int* __restrict__ dst, int* __restrict__ cnt) {
    for (int e = blockIdx.x * blockDim.x + threadIdx.x; e < NE; e += gridDim.x * blockDim.x)
        atomicAdd(&cnt[dst[e]], 1);
}

// phase 1: per-block sums of cnt
__global__ __launch_bounds__(1024) void k_bsum(const int* __restrict__ cnt, int* __restrict__ bsum) {
    __shared__ int s[1024];
    const int t = threadIdx.x;
    int gid = blockIdx.x * 1024 + t;
    s[t] = (gid < NN) ? cnt[gid] : 0;
    __syncthreads();
    for (int st = 512; st >= 1; st >>= 1) {
        if (t < st) s[t] += s[t + st];
        __syncthreads();
    }
    if (t == 0) bsum[blockIdx.x] = s[0];
}

// phase 2: exclusive scan of the 98 block sums (one tiny block)
__global__ void k_bscan(int* __restrict__ bsum) {
    __shared__ int s[128];
    const int t = threadIdx.x;
    int v = (t < SCAN_NB) ? bsum[t] : 0;
    s[t] = v;
    __syncthreads();
    for (int st = 1; st < 128; st <<= 1) {
        int u = (t >= st) ? s[t - st] : 0;
        __syncthreads();
        s[t] += u;
        __syncthreads();
    }
    if (t < SCAN_NB) bsum[t] = s[t] - v;  // exclusive prefix
}

// phase 3: in-block inclusive scan + block prefix -> off/cur
__global__ __launch_bounds__(1024) void k_offs(const int* __restrict__ cnt, const int* __restrict__ bsum,
                                               int* __restrict__ off, int* __restrict__ cur) {
    __shared__ int s[1024];
    const int t = threadIdx.x;
    int gid = blockIdx.x * 1024 + t;
    int v = (gid < NN) ? cnt[gid] : 0;
    s[t] = v;
    __syncthreads();
    for (int st = 1; st < 1024; st <<= 1) {
        int u = (t >= st) ? s[t - st] : 0;
        __syncthreads();
        s[t] += u;
        __syncthreads();
    }
    int excl = s[t] - v + bsum[blockIdx.x];
    if (gid < NN) { off[gid] = excl; cur[gid] = excl; }
    if (gid == 0) off[NN] = NE;  // every dst < NN, so total == NE
}

__global__ __launch_bounds__(256) void k_scatter(const int* __restrict__ src, const int* __restrict__ dst,
                                                 int* __restrict__ cur, int* __restrict__ ss) {
    for (int e = blockIdx.x * blockDim.x + threadIdx.x; e < NE; e += gridDim.x * blockDim.x) {
        int p = atomicAdd(&cur[dst[e]], 1);
        ss[p] = src[e];
    }
}

// ---------------- bf16 helpers ----------------
__device__ __forceinline__ float bf_lo(unsigned u) { return __uint_as_float(u << 16); }
__device__ __forceinline__ float bf_hi(unsigned u) { return __uint_as_float(u & 0xFFFF0000u); }
__device__ __forceinline__ unsigned pack_bf16(float a, float b) {
    unsigned ua = __float_as_uint(a), ub = __float_as_uint(b);
    ua = (ua + 0x7FFFu + ((ua >> 16) & 1u)) >> 16;
    ub = (ub + 0x7FFFu + ((ub >> 16) & 1u)) >> 16;
    return (ub << 16) | ua;
}

// x (fp32 [NN][128]) -> packed bf16 [NN][64 uints]
__global__ __launch_bounds__(256) void k_xcast(const float* __restrict__ x, unsigned* __restrict__ xb) {
    int gid = blockIdx.x * blockDim.x + threadIdx.x;
    if (gid >= NN * 64) return;
    int i = gid >> 6, ln = gid & 63;
    float2 v = *(const float2*)(x + (size_t)i * DD + 2 * ln);
    xb[gid] = pack_bf16(v.x, v.y);
}

// ---------------- gather: one wave per node, no LDS, no barriers ----------------
__global__ __launch_bounds__(256) void k_gather(const unsigned* __restrict__ zb,
                                                const int* __restrict__ off, const int* __restrict__ ss,
                                                unsigned* __restrict__ aggb) {
    const int wv = threadIdx.x >> 6, ln = threadIdx.x & 63;
    const int i = blockIdx.x * 4 + wv;
    if (i >= NN) return;
    unsigned u = zb[(size_t)i * 64 + ln];
    float ax = bf_lo(u), ay = bf_hi(u);
    const int e0 = off[i], e1 = off[i + 1];
    int k = e0;
    for (; k + 8 <= e1; k += 8) {
        int i0 = ss[k], i1 = ss[k + 1], i2 = ss[k + 2], i3 = ss[k + 3];
        int i4 = ss[k + 4], i5 = ss[k + 5], i6 = ss[k + 6], i7 = ss[k + 7];
        unsigned u0 = zb[(size_t)i0 * 64 + ln], u1 = zb[(size_t)i1 * 64 + ln];
        unsigned u2 = zb[(size_t)i2 * 64 + ln], u3 = zb[(size_t)i3 * 64 + ln];
        unsigned u4 = zb[(size_t)i4 * 64 + ln], u5 = zb[(size_t)i5 * 64 + ln];
        unsigned u6 = zb[(size_t)i6 * 64 + ln], u7 = zb[(size_t)i7 * 64 + ln];
        ax += bf_lo(u0) + bf_lo(u1) + bf_lo(u2) + bf_lo(u3)
            + bf_lo(u4) + bf_lo(u5) + bf_lo(u6) + bf_lo(u7);
        ay += bf_hi(u0) + bf_hi(u1) + bf_hi(u2) + bf_hi(u3)
            + bf_hi(u4) + bf_hi(u5) + bf_hi(u6) + bf_hi(u7);
    }
    for (; k < e1; ++k) {
        unsigned uu = zb[(size_t)ss[k] * 64 + ln];
        ax += bf_lo(uu); ay += bf_hi(uu);
    }
    aggb[(size_t)i * 64 + ln] = pack_bf16(ax, ay);
}

// ---------------- MLP + BN-stats (uniform work per block) ----------------
__device__ __forceinline__ void tile_gemm(const float (*A)[DD + 4], const float* __restrict__ W,
                                          const float* __restrict__ bias, int r0, int c0,
                                          float acc[2][8]) {
    const float4 ba = *(const float4*)(bias + c0);
    const float4 bb = *(const float4*)(bias + c0 + 4);
#pragma unroll
    for (int i = 0; i < 2; i++) {
        acc[i][0] = ba.x; acc[i][1] = ba.y; acc[i][2] = ba.z; acc[i][3] = ba.w;
        acc[i][4] = bb.x; acc[i][5] = bb.y; acc[i][6] = bb.z; acc[i][7] = bb.w;
    }
    for (int k = 0; k < DD; k += 4) {
        float4 a0 = *(const float4*)&A[r0][k];
        float4 a1 = *(const float4*)&A[r0 + 1][k];
        float av0[4] = {a0.x, a0.y, a0.z, a0.w};
        float av1[4] = {a1.x, a1.y, a1.z, a1.w};
#pragma unroll
        for (int kk = 0; kk < 4; kk++) {
            const float* wr = W + (k + kk) * DD + c0;
            float4 wa = *(const float4*)wr;
            float4 wb = *(const float4*)(wr + 4);
            float w[8] = {wa.x, wa.y, wa.z, wa.w, wb.x, wb.y, wb.z, wb.w};
#pragma unroll
            for (int j = 0; j < 8; j++) {
                acc[0][j] = fmaf(av0[kk], w[j], acc[0][j]);
                acc[1][j] = fmaf(av1[kk], w[j], acc[1][j]);
            }
        }
    }
}

__global__ __launch_bounds__(256) void k_mlp(
    const unsigned* __restrict__ aggb,
    const float* __restrict__ W1, const float* __restrict__ b1,
    const float* __restrict__ W2, const float* __restrict__ b2,
    float* __restrict__ hout,  // d_out + l*128, row stride ZCOLS; raw h
    float* __restrict__ s1, float* __restrict__ s2) {
    __shared__ float buf[TM][DD + 4];
    const int tid = threadIdx.x;
    const int node0 = blockIdx.x * TM;

    // stage agg tile (bf16 -> fp32 LDS)
    for (int idx = tid; idx < TM * 64; idx += 256) {
        int r = idx >> 6, c = idx & 63;
        int node = node0 + r;
        unsigned u = (node < NN) ? aggb[(size_t)node * 64 + c] : 0u;
        buf[r][2 * c] = bf_lo(u);
        buf[r][2 * c + 1] = bf_hi(u);
    }
    __syncthreads();

    const int tx = tid & 15, ty = tid >> 4;
    const int c0 = tx * 8, r0 = ty * 2;

    // ---- GEMM1 + ReLU ----
    float acc[2][8];
    tile_gemm(buf, W1, b1, r0, c0, acc);
    float r1[2][8];
#pragma unroll
    for (int i = 0; i < 2; i++)
#pragma unroll
        for (int j = 0; j < 8; j++) r1[i][j] = fmaxf(acc[i][j], 0.f);
    __syncthreads();  // done reading buf(agg)
#pragma unroll
    for (int i = 0; i < 2; i++)
#pragma unroll
        for (int j = 0; j < 8; j++) buf[r0 + i][c0 + j] = r1[i][j];
    __syncthreads();

    // ---- GEMM2 -> raw h ----
    tile_gemm(buf, W2, b2, r0, c0, acc);

#pragma unroll
    for (int i = 0; i < 2; i++) {
        int node = node0 + r0 + i;
        if (node < NN) {
            float* op = hout + (size_t)node * ZCOLS + c0;
            *(float4*)op = make_float4(acc[i][0], acc[i][1], acc[i][2], acc[i][3]);
            *(float4*)(op + 4) = make_float4(acc[i][4], acc[i][5], acc[i][6], acc[i][7]);
        }
    }

    // ---- per-block column sum / sumsq -> global atomics ----
    float sv[8], qv[8];
#pragma unroll
    for (int j = 0; j < 8; j++) { sv[j] = 0.f; qv[j] = 0.f; }
#pragma unroll
    for (int i = 0; i < 2; i++) {
        if (node0 + r0 + i < NN) {
#pragma unroll
            for (int j = 0; j < 8; j++) { float v = acc[i][j]; sv[j] += v; qv[j] += v * v; }
        }
    }
    float2* red = (float2*)&buf[0][0];  // 16 KB, fits
    __syncthreads();                    // done reading buf(h1)
#pragma unroll
    for (int j = 0; j < 8; j++) red[ty * DD + c0 + j] = make_float2(sv[j], qv[j]);
    __syncthreads();
    for (int st = 8; st >= 1; st >>= 1) {
        if (ty < st) {
#pragma unroll
            for (int j = 0; j < 8; j++) {
                float2 a = red[ty * DD + c0 + j];
                float2 b = red[(ty + st) * DD + c0 + j];
                red[ty * DD + c0 + j] = make_float2(a.x + b.x, a.y + b.y);
            }
        }
        __syncthreads();
    }
    if (tid < DD) {
        float2 v = red[tid];
        atomicAdd(&s1[tid], v.x);
        atomicAdd(&s2[tid], v.y);
    }
}

// ---------------- BN finalize+apply (+optional packed-bf16 z emit) ----------------
__global__ __launch_bounds__(256) void k_bnapply(float* __restrict__ hout,
                                                 const float* __restrict__ s1, const float* __restrict__ s2,
                                                 const float* __restrict__ gamma, const float* __restrict__ beta,
                                                 unsigned* __restrict__ zb_out, int relu) {
    int gid = blockIdx.x * blockDim.x + threadIdx.x;
    if (gid >= NN * 32) return;
    int i = gid >> 5, q = gid & 31;
    int c = q * 4;
    float4 m4 = *(const float4*)(s1 + c);
    float4 q4 = *(const float4*)(s2 + c);
    float4 g4 = *(const float4*)(gamma + c);
    float4 be4 = *(const float4*)(beta + c);
    float A[4], B[4];
    {
        float m[4] = {m4.x, m4.y, m4.z, m4.w};
        float s[4] = {q4.x, q4.y, q4.z, q4.w};
        float g[4] = {g4.x, g4.y, g4.z, g4.w};
        float bb[4] = {be4.x, be4.y, be4.z, be4.w};
#pragma unroll
        for (int j = 0; j < 4; j++) {
            float mean = m[j] * (1.0f / NN);
            float var = s[j] * (1.0f / NN) - mean * mean;
            float a = g[j] * rsqrtf(var + 1e-5f);
            A[j] = a;
            B[j] = bb[j] - mean * a;
        }
    }
    float4* p = (float4*)(hout + (size_t)i * ZCOLS + c);
    float4 v = *p;
    v.x = v.x * A[0] + B[0];
    v.y = v.y * A[1] + B[1];
    v.z = v.z * A[2] + B[2];
    v.w = v.w * A[3] + B[3];
    if (relu) {
        v.x = fmaxf(v.x, 0.f); v.y = fmaxf(v.y, 0.f);
        v.z = fmaxf(v.z, 0.f); v.w = fmaxf(v.w, 0.f);
    }
    *p = v;
    if (zb_out) {
        uint2 w;
        w.x = pack_bf16(v.x, v.y);
        w.y = pack_bf16(v.z, v.w);
        *(uint2*)(zb_out + (size_t)i * 64 + 2 * q) = w;
    }
}

// ---------------- graph pooling (batch is sorted) ----------------
__global__ __launch_bounds__(256) void k_pool(const float* __restrict__ zc, const int* __restrict__ batch,
                                              float* __restrict__ g) {
    const int gr = blockIdx.x;
    int lo = 0, hi = NN;
    while (lo < hi) { int mid = (lo + hi) >> 1; if (batch[mid] < gr) lo = mid + 1; else hi = mid; }
    const int start = lo;
    hi = NN;
    while (lo < hi) { int mid = (lo + hi) >> 1; if (batch[mid] < gr + 1) lo = mid + 1; else hi = mid; }
    const int end = lo;

    const int tid = threadIdx.x;
    const int h = tid >> 7, c = tid & 127;
    float a0 = 0.f, a1 = 0.f, a2 = 0.f;
    for (int r = start + h; r < end; r += 2) {
        const float* row = zc + (size_t)r * ZCOLS;
        a0 += row[c];
        a1 += row[c + DD];
        a2 += row[c + 2 * DD];
    }
    __shared__ float red[3][256];
    red[0][tid] = a0; red[1][tid] = a1; red[2][tid] = a2;
    __syncthreads();
    if (tid < 128) {
        float* gp = g + (size_t)gr * ZCOLS;
        gp[c] = red[0][tid] + red[0][tid + 128];
        gp[c + DD] = red[1][tid] + red[1][tid + 128];
        gp[c + 2 * DD] = red[2][tid] + red[2][tid + 128];
    }
}

extern "C" void kernel_launch(void* const* d_in, const int* in_sizes, int n_in,
                              void* d_out, int out_size, void* d_ws, size_t ws_size,
                              hipStream_t stream) {
    const float* x = (const float*)d_in[0];
    const int* ei = (const int*)d_in[1];
    const int* batch = (const int*)d_in[2];
    const float* W1 = (const float*)d_in[3];
    const float* b1 = (const float*)d_in[4];
    const float* W2 = (const float*)d_in[5];
    const float* b2 = (const float*)d_in[6];
    const float* gamma = (const float*)d_in[7];
    const float* beta = (const float*)d_in[8];
    float* out = (float*)d_out;

    const int* esrc = ei;        // edge_index[0]
    const int* edst = ei + NE;   // edge_index[1]

    int* cnt = (int*)d_ws;            // N
    int* off = cnt + NN;              // N+1
    int* cur = off + NN + 1;          // N
    int* bsum = cur + NN;             // SCAN_NB (98)
    int* ss = bsum + 128;             // E
    float* st = (float*)(ss + NE);    // 3 layers x 2 x 128 stats
    uintptr_t zbase = (uintptr_t)(st + 6 * DD);
    zbase = (zbase + 255) & ~(uintptr_t)255;
    unsigned* bufA = (unsigned*)zbase;              // z bf16 (recycled each layer)
    unsigned* bufB = bufA + (size_t)NN * 64;        // agg bf16 (recycled each layer)

    hipMemsetAsync(cnt, 0, NN * sizeof(int), stream);
    hipMemsetAsync(st, 0, 6 * DD * sizeof(float), stream);
    k_hist<<<2048, 256, 0, stream>>>(edst, cnt);
    k_bsum<<<SCAN_NB, 1024, 0, stream>>>(cnt, bsum);
    k_bscan<<<1, 128, 0, stream>>>(bsum);
    k_offs<<<SCAN_NB, 1024, 0, stream>>>(cnt, bsum, off, cur);
    k_scatter<<<2048, 256, 0, stream>>>(esrc, edst, cur, ss);
    k_xcast<<<(NN * 64 + 255) / 256, 256, 0, stream>>>(x, bufA);

    float* gout = out + (size_t)NN * ZCOLS;
    for (int l = 0; l < 3; l++) {
        float* s1 = st + l * 2 * DD;
        float* s2 = s1 + DD;
        k_gather<<<(NN + 3) / 4, 256, 0, stream>>>(bufA, off, ss, bufB);
        k_mlp<<<(NN + TM - 1) / TM, 256, 0, stream>>>(
            bufB, W1 + l * DD * DD, b1 + l * DD, W2 + l * DD * DD, b2 + l * DD,
            out + l * DD, s1, s2);
        k_bnapply<<<(NN * 32 + 255) / 256, 256, 0, stream>>>(
            out + l * DD, s1, s2, gamma + l * DD, beta + l * DD,
            (l < 2) ? bufA : nullptr, (l < 2) ? 1 : 0);
    }
    k_pool<<<NG, 256, 0, stream>>>(out, batch, gout);
}

// Round 9
// 1104.803 us; speedup vs baseline: 1.4306x; 1.2174x over previous
//
#include <hip/hip_runtime.h>

#define NN 100000
#define NE 1600000
#define DD 128
#define NG 512
#define ZCOLS 384
#define TM 32
#define SCAN_NB ((NN + 1023) / 1024)  // 98

// ---------------- CSR build (counting sort by dst) ----------------
__global__ __launch_bounds__(256) void k_hist(const int* __restrict__ dst, int* __restrict__ cnt) {
    for (int e = blockIdx.x * blockDim.x + threadIdx.x; e < NE; e += gridDim.x * blockDim.x)
        atomicAdd(&cnt[dst[e]], 1);
}

__global__ __launch_bounds__(1024) void k_bsum(const int* __restrict__ cnt, int* __restrict__ bsum) {
    __shared__ int s[1024];
    const int t = threadIdx.x;
    int gid = blockIdx.x * 1024 + t;
    s[t] = (gid < NN) ? cnt[gid] : 0;
    __syncthreads();
    for (int st = 512; st >= 1; st >>= 1) {
        if (t < st) s[t] += s[t + st];
        __syncthreads();
    }
    if (t == 0) bsum[blockIdx.x] = s[0];
}

__global__ void k_bscan(int* __restrict__ bsum) {
    __shared__ int s[128];
    const int t = threadIdx.x;
    int v = (t < SCAN_NB) ? bsum[t] : 0;
    s[t] = v;
    __syncthreads();
    for (int st = 1; st < 128; st <<= 1) {
        int u = (t >= st) ? s[t - st] : 0;
        __syncthreads();
        s[t] += u;
        __syncthreads();
    }
    if (t < SCAN_NB) bsum[t] = s[t] - v;  // exclusive prefix
}

__global__ __launch_bounds__(1024) void k_offs(const int* __restrict__ cnt, const int* __restrict__ bsum,
                                               int* __restrict__ off, int* __restrict__ cur) {
    __shared__ int s[1024];
    const int t = threadIdx.x;
    int gid = blockIdx.x * 1024 + t;
    int v = (gid < NN) ? cnt[gid] : 0;
    s[t] = v;
    __syncthreads();
    for (int st = 1; st < 1024; st <<= 1) {
        int u = (t >= st) ? s[t - st] : 0;
        __syncthreads();
        s[t] += u;
        __syncthreads();
    }
    int excl = s[t] - v + bsum[blockIdx.x];
    if (gid < NN) { off[gid] = excl; cur[gid] = excl; }
    if (gid == 0) off[NN] = NE;
}

__global__ __launch_bounds__(256) void k_scatter(const int* __restrict__ src, const int* __restrict__ dst,
                                                 int* __restrict__ cur, int* __restrict__ ss) {
    for (int e = blockIdx.x * blockDim.x + threadIdx.x; e < NE; e += gridDim.x * blockDim.x) {
        int p = atomicAdd(&cur[dst[e]], 1);
        ss[p] = src[e];
    }
}

// ---------------- bf16 helpers ----------------
__device__ __forceinline__ float bf_lo(unsigned u) { return __uint_as_float(u << 16); }
__device__ __forceinline__ float bf_hi(unsigned u) { return __uint_as_float(u & 0xFFFF0000u); }
__device__ __forceinline__ unsigned pack_bf16(float a, float b) {
    unsigned ua = __float_as_uint(a), ub = __float_as_uint(b);
    ua = (ua + 0x7FFFu + ((ua >> 16) & 1u)) >> 16;
    ub = (ub + 0x7FFFu + ((ub >> 16) & 1u)) >> 16;
    return (ub << 16) | ua;
}

__global__ __launch_bounds__(256) void k_xcast(const float* __restrict__ x, unsigned* __restrict__ xb) {
    int gid = blockIdx.x * blockDim.x + threadIdx.x;
    if (gid >= NN * 64) return;
    int i = gid >> 6, ln = gid & 63;
    float2 v = *(const float2*)(x + (size_t)i * DD + 2 * ln);
    xb[gid] = pack_bf16(v.x, v.y);
}

// ---------------- gather: one wave per node, no LDS, no barriers ----------------
__global__ __launch_bounds__(256) void k_gather(const unsigned* __restrict__ zb,
                                                const int* __restrict__ off, const int* __restrict__ ss,
                                                unsigned* __restrict__ aggb) {
    const int wv = threadIdx.x >> 6, ln = threadIdx.x & 63;
    const int i = blockIdx.x * 4 + wv;
    if (i >= NN) return;
    unsigned u = zb[(size_t)i * 64 + ln];
    float ax = bf_lo(u), ay = bf_hi(u);
    const int e0 = off[i], e1 = off[i + 1];
    int k = e0;
    for (; k + 8 <= e1; k += 8) {
        int i0 = ss[k], i1 = ss[k + 1], i2 = ss[k + 2], i3 = ss[k + 3];
        int i4 = ss[k + 4], i5 = ss[k + 5], i6 = ss[k + 6], i7 = ss[k + 7];
        unsigned u0 = zb[(size_t)i0 * 64 + ln], u1 = zb[(size_t)i1 * 64 + ln];
        unsigned u2 = zb[(size_t)i2 * 64 + ln], u3 = zb[(size_t)i3 * 64 + ln];
        unsigned u4 = zb[(size_t)i4 * 64 + ln], u5 = zb[(size_t)i5 * 64 + ln];
        unsigned u6 = zb[(size_t)i6 * 64 + ln], u7 = zb[(size_t)i7 * 64 + ln];
        ax += bf_lo(u0) + bf_lo(u1) + bf_lo(u2) + bf_lo(u3)
            + bf_lo(u4) + bf_lo(u5) + bf_lo(u6) + bf_lo(u7);
        ay += bf_hi(u0) + bf_hi(u1) + bf_hi(u2) + bf_hi(u3)
            + bf_hi(u4) + bf_hi(u5) + bf_hi(u6) + bf_hi(u7);
    }
    for (; k < e1; ++k) {
        unsigned uu = zb[(size_t)ss[k] * 64 + ln];
        ax += bf_lo(uu); ay += bf_hi(uu);
    }
    aggb[(size_t)i * 64 + ln] = pack_bf16(ax, ay);
}

// ---------------- MLP + BN-stats; W staged in LDS in 64-row halves ----------------
// Thread (tx,ty) owns rows r0=ty*2..+1, cols {tx*4..tx*4+3} and {64+tx*4..+3}
// (split columns -> 2-way (free) LDS bank aliasing on W reads instead of 4-way).
__device__ __forceinline__ void gemm_half(const float (*A)[DD + 4], const float* __restrict__ Wl,
                                          int kbase, int r0, int tx, float acc[2][8]) {
    for (int k = 0; k < 64; k += 4) {
        float4 a0 = *(const float4*)&A[r0][kbase + k];
        float4 a1 = *(const float4*)&A[r0 + 1][kbase + k];
        float av0[4] = {a0.x, a0.y, a0.z, a0.w};
        float av1[4] = {a1.x, a1.y, a1.z, a1.w};
#pragma unroll
        for (int kk = 0; kk < 4; kk++) {
            const float* wr = Wl + (k + kk) * DD;
            float4 wa = *(const float4*)(wr + tx * 4);
            float4 wb = *(const float4*)(wr + 64 + tx * 4);
            float w[8] = {wa.x, wa.y, wa.z, wa.w, wb.x, wb.y, wb.z, wb.w};
#pragma unroll
            for (int j = 0; j < 8; j++) {
                acc[0][j] = fmaf(av0[kk], w[j], acc[0][j]);
                acc[1][j] = fmaf(av1[kk], w[j], acc[1][j]);
            }
        }
    }
}

__device__ __forceinline__ void stage_w(float* __restrict__ wlds, const float* __restrict__ Wsrc,
                                        int tid) {
    // 64 rows x 128 cols fp32 = 2048 float4, 8 per thread, coalesced
    const float4* src = (const float4*)Wsrc;
    float4* dst = (float4*)wlds;
#pragma unroll
    for (int it = 0; it < 8; it++) dst[tid + 256 * it] = src[tid + 256 * it];
}

__global__ __launch_bounds__(256) void k_mlp(
    const unsigned* __restrict__ aggb,
    const float* __restrict__ W1, const float* __restrict__ b1,
    const float* __restrict__ W2, const float* __restrict__ b2,
    float* __restrict__ hout,  // d_out + l*128, row stride ZCOLS; raw h
    float* __restrict__ s1, float* __restrict__ s2) {
    __shared__ float buf[TM][DD + 4];     // 16.9 KB: agg -> h1 -> BN-red
    __shared__ float wlds[64 * DD];       // 32 KB: one 64-row half of W
    const int tid = threadIdx.x;
    const int node0 = blockIdx.x * TM;

    // stage agg tile (bf16 -> fp32 LDS) + W1 half 0
    for (int idx = tid; idx < TM * 64; idx += 256) {
        int r = idx >> 6, c = idx & 63;
        int node = node0 + r;
        unsigned u = (node < NN) ? aggb[(size_t)node * 64 + c] : 0u;
        buf[r][2 * c] = bf_lo(u);
        buf[r][2 * c + 1] = bf_hi(u);
    }
    stage_w(wlds, W1, tid);
    __syncthreads();

    const int tx = tid & 15, ty = tid >> 4;
    const int r0 = ty * 2;

    // ---- GEMM1 ----
    float acc[2][8];
    {
        float4 ba = *(const float4*)(b1 + tx * 4);
        float4 bb = *(const float4*)(b1 + 64 + tx * 4);
#pragma unroll
        for (int i = 0; i < 2; i++) {
            acc[i][0] = ba.x; acc[i][1] = ba.y; acc[i][2] = ba.z; acc[i][3] = ba.w;
            acc[i][4] = bb.x; acc[i][5] = bb.y; acc[i][6] = bb.z; acc[i][7] = bb.w;
        }
    }
    gemm_half(buf, wlds, 0, r0, tx, acc);
    __syncthreads();
    stage_w(wlds, W1 + 64 * DD, tid);
    __syncthreads();
    gemm_half(buf, wlds, 64, r0, tx, acc);

    float r1[2][8];
#pragma unroll
    for (int i = 0; i < 2; i++)
#pragma unroll
        for (int j = 0; j < 8; j++) r1[i][j] = fmaxf(acc[i][j], 0.f);
    __syncthreads();  // done reading buf(agg) + wlds(W1h1)

    // h1 -> buf; stage W2 half 0
#pragma unroll
    for (int i = 0; i < 2; i++) {
#pragma unroll
        for (int j = 0; j < 4; j++) {
            buf[r0 + i][tx * 4 + j] = r1[i][j];
            buf[r0 + i][64 + tx * 4 + j] = r1[i][4 + j];
        }
    }
    stage_w(wlds, W2, tid);
    __syncthreads();

    // ---- GEMM2 ----
    {
        float4 ba = *(const float4*)(b2 + tx * 4);
        float4 bb = *(const float4*)(b2 + 64 + tx * 4);
#pragma unroll
        for (int i = 0; i < 2; i++) {
            acc[i][0] = ba.x; acc[i][1] = ba.y; acc[i][2] = ba.z; acc[i][3] = ba.w;
            acc[i][4] = bb.x; acc[i][5] = bb.y; acc[i][6] = bb.z; acc[i][7] = bb.w;
        }
    }
    gemm_half(buf, wlds, 0, r0, tx, acc);
    __syncthreads();
    stage_w(wlds, W2 + 64 * DD, tid);
    __syncthreads();
    gemm_half(buf, wlds, 64, r0, tx, acc);

    // store raw h
#pragma unroll
    for (int i = 0; i < 2; i++) {
        int node = node0 + r0 + i;
        if (node < NN) {
            float* op = hout + (size_t)node * ZCOLS;
            *(float4*)(op + tx * 4) = make_float4(acc[i][0], acc[i][1], acc[i][2], acc[i][3]);
            *(float4*)(op + 64 + tx * 4) = make_float4(acc[i][4], acc[i][5], acc[i][6], acc[i][7]);
        }
    }

    // ---- per-block column sum / sumsq -> global atomics ----
    float sv[8], qv[8];
#pragma unroll
    for (int j = 0; j < 8; j++) { sv[j] = 0.f; qv[j] = 0.f; }
#pragma unroll
    for (int i = 0; i < 2; i++) {
        if (node0 + r0 + i < NN) {
#pragma unroll
            for (int j = 0; j < 8; j++) { float v = acc[i][j]; sv[j] += v; qv[j] += v * v; }
        }
    }
    float2* red = (float2*)&buf[0][0];  // [16][128] float2 = 16 KB
    __syncthreads();                    // done reading buf(h1) + wlds
#pragma unroll
    for (int j = 0; j < 4; j++) {
        red[ty * DD + tx * 4 + j] = make_float2(sv[j], qv[j]);
        red[ty * DD + 64 + tx * 4 + j] = make_float2(sv[4 + j], qv[4 + j]);
    }
    __syncthreads();
    for (int st = 8; st >= 1; st >>= 1) {
        if (ty < st) {
#pragma unroll
            for (int j = 0; j < 4; j++) {
                float2 a = red[ty * DD + tx * 4 + j];
                float2 b = red[(ty + st) * DD + tx * 4 + j];
                red[ty * DD + tx * 4 + j] = make_float2(a.x + b.x, a.y + b.y);
                a = red[ty * DD + 64 + tx * 4 + j];
                b = red[(ty + st) * DD + 64 + tx * 4 + j];
                red[ty * DD + 64 + tx * 4 + j] = make_float2(a.x + b.x, a.y + b.y);
            }
        }
        __syncthreads();
    }
    if (tid < DD) {
        float2 v = red[tid];
        atomicAdd(&s1[tid], v.x);
        atomicAdd(&s2[tid], v.y);
    }
}

// ---------------- BN finalize+apply (+optional packed-bf16 z emit) ----------------
__global__ __launch_bounds__(256) void k_bnapply(float* __restrict__ hout,
                                                 const float* __restrict__ s1, const float* __restrict__ s2,
                                                 const float* __restrict__ gamma, const float* __restrict__ beta,
                                                 unsigned* __restrict__ zb_out, int relu) {
    int gid = blockIdx.x * blockDim.x + threadIdx.x;
    if (gid >= NN * 32) return;
    int i = gid >> 5, q = gid & 31;
    int c = q * 4;
    float4 m4 = *(const float4*)(s1 + c);
    float4 q4 = *(const float4*)(s2 + c);
    float4 g4 = *(const float4*)(gamma + c);
    float4 be4 = *(const float4*)(beta + c);
    float A[4], B[4];
    {
        float m[4] = {m4.x, m4.y, m4.z, m4.w};
        float s[4] = {q4.x, q4.y, q4.z, q4.w};
        float g[4] = {g4.x, g4.y, g4.z, g4.w};
        float bb[4] = {be4.x, be4.y, be4.z, be4.w};
#pragma unroll
        for (int j = 0; j < 4; j++) {
            float mean = m[j] * (1.0f / NN);
            float var = s[j] * (1.0f / NN) - mean * mean;
            float a = g[j] * rsqrtf(var + 1e-5f);
            A[j] = a;
            B[j] = bb[j] - mean * a;
        }
    }
    float4* p = (float4*)(hout + (size_t)i * ZCOLS + c);
    float4 v = *p;
    v.x = v.x * A[0] + B[0];
    v.y = v.y * A[1] + B[1];
    v.z = v.z * A[2] + B[2];
    v.w = v.w * A[3] + B[3];
    if (relu) {
        v.x = fmaxf(v.x, 0.f); v.y = fmaxf(v.y, 0.f);
        v.z = fmaxf(v.z, 0.f); v.w = fmaxf(v.w, 0.f);
    }
    *p = v;
    if (zb_out) {
        uint2 w;
        w.x = pack_bf16(v.x, v.y);
        w.y = pack_bf16(v.z, v.w);
        *(uint2*)(zb_out + (size_t)i * 64 + 2 * q) = w;
    }
}

// ---------------- graph pooling (batch is sorted) ----------------
__global__ __launch_bounds__(256) void k_pool(const float* __restrict__ zc, const int* __restrict__ batch,
                                              float* __restrict__ g) {
    const int gr = blockIdx.x;
    int lo = 0, hi = NN;
    while (lo < hi) { int mid = (lo + hi) >> 1; if (batch[mid] < gr) lo = mid + 1; else hi = mid; }
    const int start = lo;
    hi = NN;
    while (lo < hi) { int mid = (lo + hi) >> 1; if (batch[mid] < gr + 1) lo = mid + 1; else hi = mid; }
    const int end = lo;

    const int tid = threadIdx.x;
    const int h = tid >> 7, c = tid & 127;
    float a0 = 0.f, a1 = 0.f, a2 = 0.f;
    for (int r = start + h; r < end; r += 2) {
        const float* row = zc + (size_t)r * ZCOLS;
        a0 += row[c];
        a1 += row[c + DD];
        a2 += row[c + 2 * DD];
    }
    __shared__ float red[3][256];
    red[0][tid] = a0; red[1][tid] = a1; red[2][tid] = a2;
    __syncthreads();
    if (tid < 128) {
        float* gp = g + (size_t)gr * ZCOLS;
        gp[c] = red[0][tid] + red[0][tid + 128];
        gp[c + DD] = red[1][tid] + red[1][tid + 128];
        gp[c + 2 * DD] = red[2][tid] + red[2][tid + 128];
    }
}

extern "C" void kernel_launch(void* const* d_in, const int* in_sizes, int n_in,
                              void* d_out, int out_size, void* d_ws, size_t ws_size,
                              hipStream_t stream) {
    const float* x = (const float*)d_in[0];
    const int* ei = (const int*)d_in[1];
    const int* batch = (const int*)d_in[2];
    const float* W1 = (const float*)d_in[3];
    const float* b1 = (const float*)d_in[4];
    const float* W2 = (const float*)d_in[5];
    const float* b2 = (const float*)d_in[6];
    const float* gamma = (const float*)d_in[7];
    const float* beta = (const float*)d_in[8];
    float* out = (float*)d_out;

    const int* esrc = ei;        // edge_index[0]
    const int* edst = ei + NE;   // edge_index[1]

    int* cnt = (int*)d_ws;            // N
    int* off = cnt + NN;              // N+1
    int* cur = off + NN + 1;          // N
    int* bsum = cur + NN;             // SCAN_NB (98)
    int* ss = bsum + 128;             // E
    float* st = (float*)(ss + NE);    // 3 layers x 2 x 128 stats
    uintptr_t zbase = (uintptr_t)(st + 6 * DD);
    zbase = (zbase + 255) & ~(uintptr_t)255;
    unsigned* bufA = (unsigned*)zbase;              // z bf16 (recycled each layer)
    unsigned* bufB = bufA + (size_t)NN * 64;        // agg bf16 (recycled each layer)

    hipMemsetAsync(cnt, 0, NN * sizeof(int), stream);
    hipMemsetAsync(st, 0, 6 * DD * sizeof(float), stream);
    k_hist<<<2048, 256, 0, stream>>>(edst, cnt);
    k_bsum<<<SCAN_NB, 1024, 0, stream>>>(cnt, bsum);
    k_bscan<<<1, 128, 0, stream>>>(bsum);
    k_offs<<<SCAN_NB, 1024, 0, stream>>>(cnt, bsum, off, cur);
    k_scatter<<<2048, 256, 0, stream>>>(esrc, edst, cur, ss);
    k_xcast<<<(NN * 64 + 255) / 256, 256, 0, stream>>>(x, bufA);

    float* gout = out + (size_t)NN * ZCOLS;
    for (int l = 0; l < 3; l++) {
        float* s1 = st + l * 2 * DD;
        float* s2 = s1 + DD;
        k_gather<<<(NN + 3) / 4, 256, 0, stream>>>(bufA, off, ss, bufB);
        k_mlp<<<(NN + TM - 1) / TM, 256, 0, stream>>>(
            bufB, W1 + l * DD * DD, b1 + l * DD, W2 + l * DD * DD, b2 + l * DD,
            out + l * DD, s1, s2);
        k_bnapply<<<(NN * 32 + 255) / 256, 256, 0, stream>>>(
            out + l * DD, s1, s2, gamma + l * DD, beta + l * DD,
            (l < 2) ? bufA : nullptr, (l < 2) ? 1 : 0);
    }
    k_pool<<<NG, 256, 0, stream>>>(out, batch, gout);
}